// Round 1
// baseline (740.254 us; speedup 1.0000x reference)
//
#include <hip/hip_runtime.h>
#include <hip/hip_bf16.h>
#include <stdint.h>

typedef __attribute__((ext_vector_type(8))) short bf16x8;
typedef __attribute__((ext_vector_type(4))) float f32x4;

typedef const __attribute__((address_space(1))) void* gas_ptr;
typedef __attribute__((address_space(3))) void* lds_ptr_t;

__device__ __forceinline__ unsigned short f32_to_bf16_rtn(float x) {
    unsigned u = __float_as_uint(x);
    u += 0x7FFFu + ((u >> 16) & 1u);
    return (unsigned short)(u >> 16);
}
__device__ __forceinline__ float bf16_bits_to_f32(unsigned short h) {
    return __uint_as_float(((unsigned)h) << 16);
}

// ---------------------------------------------------------------------------
// Kernel 1: split fp32 inputs into hi/lo bf16 pairs (a = hi + lo, err ~2^-17)
// ---------------------------------------------------------------------------
__global__ __launch_bounds__(256) void split_hi_lo(
    const float* __restrict__ A, const float* __restrict__ B,
    unsigned short* __restrict__ Ahi, unsigned short* __restrict__ Alo,
    unsigned short* __restrict__ Bhi, unsigned short* __restrict__ Blo, int n4)
{
    int i = blockIdx.x * 256 + threadIdx.x;
    if (i >= n4) return;
    float4 a = ((const float4*)A)[i];
    float4 b = ((const float4*)B)[i];
    ushort4 h, l;

    h.x = f32_to_bf16_rtn(a.x); l.x = f32_to_bf16_rtn(a.x - bf16_bits_to_f32(h.x));
    h.y = f32_to_bf16_rtn(a.y); l.y = f32_to_bf16_rtn(a.y - bf16_bits_to_f32(h.y));
    h.z = f32_to_bf16_rtn(a.z); l.z = f32_to_bf16_rtn(a.z - bf16_bits_to_f32(h.z));
    h.w = f32_to_bf16_rtn(a.w); l.w = f32_to_bf16_rtn(a.w - bf16_bits_to_f32(h.w));
    ((ushort4*)Ahi)[i] = h; ((ushort4*)Alo)[i] = l;

    h.x = f32_to_bf16_rtn(b.x); l.x = f32_to_bf16_rtn(b.x - bf16_bits_to_f32(h.x));
    h.y = f32_to_bf16_rtn(b.y); l.y = f32_to_bf16_rtn(b.y - bf16_bits_to_f32(h.y));
    h.z = f32_to_bf16_rtn(b.z); l.z = f32_to_bf16_rtn(b.z - bf16_bits_to_f32(h.z));
    h.w = f32_to_bf16_rtn(b.w); l.w = f32_to_bf16_rtn(b.w - bf16_bits_to_f32(h.w));
    ((ushort4*)Bhi)[i] = h; ((ushort4*)Blo)[i] = l;
}

// ---------------------------------------------------------------------------
// Kernel 2: energies = A @ B^T via split-bf16 3-product MFMA GEMM.
// 128x128 block tile, BK=32, 256 threads (4 waves, each 64x64 = 4x4 MFMA tiles).
// PRESPLIT=true : stage pre-split bf16 tiles via global_load_lds (width 16).
// PRESPLIT=false: load fp32 tiles to registers, split inline, ds_write to LDS.
// LDS layout (no padding -- global_load_lds requires lane-contiguous):
//   [0,8K)=Ahi[128][32], [8K,16K)=Alo, [16K,24K)=Bhi, [24K,32K)=Blo
// ---------------------------------------------------------------------------
template <bool PRESPLIT>
__global__ __launch_bounds__(256) void gemm_bt_split(
    const __hip_bfloat16* __restrict__ Ahi, const __hip_bfloat16* __restrict__ Alo,
    const __hip_bfloat16* __restrict__ Bhi, const __hip_bfloat16* __restrict__ Blo,
    const float* __restrict__ Af, const float* __restrict__ Bf,
    float* __restrict__ out, int M, int N, int K)
{
    __shared__ char sm[32768];
    const int tid  = threadIdx.x;
    const int lane = tid & 63;
    const int w    = tid >> 6;
    const int bm = blockIdx.y, bn = blockIdx.x;
    const int wm = (w >> 1) * 64;   // wave row offset in block tile
    const int wn = (w & 1) * 64;    // wave col offset

    f32x4 acc[4][4] = {};

    const int rA   = lane & 15;        // fragment row/col within 16
    const int koff = (lane >> 4) << 3; // k offset 0/8/16/24

    for (int k0 = 0; k0 < K; k0 += 32) {
        __syncthreads();
        if (PRESPLIT) {
#pragma unroll
            for (int c = 0; c < 8; ++c) {
                const int t = c >> 1; // 0=Ahi 1=Alo 2=Bhi 3=Blo
                const int row = ((c & 1) << 6) + (tid >> 2);
                const __hip_bfloat16* base =
                    (t == 0) ? Ahi + (size_t)(bm * 128) * K :
                    (t == 1) ? Alo + (size_t)(bm * 128) * K :
                    (t == 2) ? Bhi + (size_t)(bn * 128) * K :
                               Blo + (size_t)(bn * 128) * K;
                const __hip_bfloat16* src = base + (size_t)row * K + k0 + ((tid & 3) << 3);
                char* dst = sm + c * 4096 + tid * 16;
                __builtin_amdgcn_global_load_lds((gas_ptr)src, (lds_ptr_t)dst, 16, 0, 0);
            }
        } else {
#pragma unroll
            for (int c = 0; c < 4; ++c) {
                const bool isA = (c < 2);
                const int rowh = ((c & 1) << 6) + (tid >> 2);
                const float* src = (isA ? Af + (size_t)(bm * 128 + rowh) * K
                                        : Bf + (size_t)(bn * 128 + rowh) * K)
                                   + k0 + ((tid & 3) << 3);
                f32x4 v0 = *(const f32x4*)src;
                f32x4 v1 = *(const f32x4*)(src + 4);
                float vv[8] = {v0.x, v0.y, v0.z, v0.w, v1.x, v1.y, v1.z, v1.w};
                bf16x8 h, l;
#pragma unroll
                for (int j = 0; j < 8; ++j) {
                    unsigned short hb = f32_to_bf16_rtn(vv[j]);
                    unsigned short lb = f32_to_bf16_rtn(vv[j] - bf16_bits_to_f32(hb));
                    h[j] = (short)hb; l[j] = (short)lb;
                }
                const int g = ((c & 1) << 12) + tid * 16;
                *(bf16x8*)(sm + (isA ? 0 : 16384) + g) = h;
                *(bf16x8*)(sm + (isA ? 8192 : 24576) + g) = l;
            }
        }
        __syncthreads();

        bf16x8 ah[4], al[4], bh[4], bl[4];
#pragma unroll
        for (int i = 0; i < 4; ++i) {
            const int ra = (wm + i * 16 + rA) * 32 + koff;
            ah[i] = *(const bf16x8*)(sm +         ra * 2);
            al[i] = *(const bf16x8*)(sm +  8192 + ra * 2);
            const int rb = (wn + i * 16 + rA) * 32 + koff;
            bh[i] = *(const bf16x8*)(sm + 16384 + rb * 2);
            bl[i] = *(const bf16x8*)(sm + 24576 + rb * 2);
        }
#pragma unroll
        for (int i = 0; i < 4; ++i)
#pragma unroll
            for (int j = 0; j < 4; ++j) {
                acc[i][j] = __builtin_amdgcn_mfma_f32_16x16x32_bf16(ah[i], bh[j], acc[i][j], 0, 0, 0);
                acc[i][j] = __builtin_amdgcn_mfma_f32_16x16x32_bf16(al[i], bh[j], acc[i][j], 0, 0, 0);
                acc[i][j] = __builtin_amdgcn_mfma_f32_16x16x32_bf16(ah[i], bl[j], acc[i][j], 0, 0, 0);
            }
    }

    // Epilogue: C/D layout col=lane&15, row=(lane>>4)*4+reg (m89/m91-verified)
    const int r0 = bm * 128 + wm + ((lane >> 4) << 2);
    const int c0 = bn * 128 + wn + (lane & 15);
#pragma unroll
    for (int i = 0; i < 4; ++i)
#pragma unroll
        for (int j = 0; j < 4; ++j)
#pragma unroll
            for (int r = 0; r < 4; ++r)
                out[(size_t)(r0 + i * 16 + r) * N + (c0 + j * 16)] = acc[i][j][r];
}

// ---------------------------------------------------------------------------
// Kernel 3: in-place row softmax, one block per row, full row in registers.
// N fixed at 8192: 256 threads x 8 float4.
// ---------------------------------------------------------------------------
__global__ __launch_bounds__(256) void softmax_rows_8192(float* __restrict__ d)
{
    const int tid = threadIdx.x;
    float4* p = (float4*)(d + (size_t)blockIdx.x * 8192);
    float4 v[8];
    float m = -3.402823466e+38f;
#pragma unroll
    for (int i = 0; i < 8; ++i) {
        v[i] = p[tid + (i << 8)];
        m = fmaxf(m, fmaxf(fmaxf(v[i].x, v[i].y), fmaxf(v[i].z, v[i].w)));
    }
#pragma unroll
    for (int o = 32; o >= 1; o >>= 1) m = fmaxf(m, __shfl_xor(m, o));
    __shared__ float smax[4], ssum[4];
    if ((tid & 63) == 0) smax[tid >> 6] = m;
    __syncthreads();
    m = fmaxf(fmaxf(smax[0], smax[1]), fmaxf(smax[2], smax[3]));

    float s = 0.f;
#pragma unroll
    for (int i = 0; i < 8; ++i) {
        v[i].x = __expf(v[i].x - m);
        v[i].y = __expf(v[i].y - m);
        v[i].z = __expf(v[i].z - m);
        v[i].w = __expf(v[i].w - m);
        s += (v[i].x + v[i].y) + (v[i].z + v[i].w);
    }
#pragma unroll
    for (int o = 32; o >= 1; o >>= 1) s += __shfl_xor(s, o);
    if ((tid & 63) == 0) ssum[tid >> 6] = s;
    __syncthreads();
    s = (ssum[0] + ssum[1]) + (ssum[2] + ssum[3]);
    const float r = 1.0f / s;
#pragma unroll
    for (int i = 0; i < 8; ++i) {
        v[i].x *= r; v[i].y *= r; v[i].z *= r; v[i].w *= r;
        p[tid + (i << 8)] = v[i];
    }
}

// ---------------------------------------------------------------------------
extern "C" void kernel_launch(void* const* d_in, const int* in_sizes, int n_in,
                              void* d_out, int out_size, void* d_ws, size_t ws_size,
                              hipStream_t stream)
{
    const float* A = (const float*)d_in[0];   // user_emb [M, K] fp32
    const float* B = (const float*)d_in[1];   // id_emb   [N, K] fp32
    float* out = (float*)d_out;               // [M, N] fp32
    const int K = 1024;
    const int M = in_sizes[0] / K;
    const int N = in_sizes[1] / K;
    const size_t elemsA = (size_t)M * K;
    const size_t elemsB = (size_t)N * K;
    const size_t need = 2 * (elemsA + elemsB) * sizeof(unsigned short);

    dim3 grid(N / 128, M / 128);
    const bool presplit = (ws_size >= need) && (M == N);

    if (presplit) {
        unsigned short* Ahi = (unsigned short*)d_ws;
        unsigned short* Alo = Ahi + elemsA;
        unsigned short* Bhi = Alo + elemsA;
        unsigned short* Blo = Bhi + elemsB;
        const int n4 = (int)(elemsA / 4);
        split_hi_lo<<<(n4 + 255) / 256, 256, 0, stream>>>(A, B, Ahi, Alo, Bhi, Blo, n4);
        gemm_bt_split<true><<<grid, 256, 0, stream>>>(
            (const __hip_bfloat16*)Ahi, (const __hip_bfloat16*)Alo,
            (const __hip_bfloat16*)Bhi, (const __hip_bfloat16*)Blo,
            nullptr, nullptr, out, M, N, K);
    } else {
        gemm_bt_split<false><<<grid, 256, 0, stream>>>(
            nullptr, nullptr, nullptr, nullptr, A, B, out, M, N, K);
    }
    softmax_rows_8192<<<M, 256, 0, stream>>>(out);
}